// Round 4
// baseline (1583.457 us; speedup 1.0000x reference)
//
#include <hip/hip_runtime.h>
#include <hip/hip_bf16.h>
#include <math.h>

// Problem constants
constexpr int B = 128;
constexpr int T = 256;
constexpr int H = 200;       // hidden
constexpr int G4 = 800;      // 4*H
constexpr int BT = B * T;    // 32768
constexpr int K0 = 360, K0P = 384;   // layer0 input dim, padded to %32
constexpr int K1 = 400, K1P = 416;   // layer1 input dim, padded to %32

typedef __bf16 bf16x8 __attribute__((ext_vector_type(8)));
typedef float f32x4 __attribute__((ext_vector_type(4)));
typedef _Float16 half2v __attribute__((ext_vector_type(2)));
typedef unsigned uix4 __attribute__((ext_vector_type(4)));

__device__ __forceinline__ float bfr2f(unsigned short u) {
  union { unsigned int i; float f; } x;
  x.i = ((unsigned int)u) << 16;
  return x.f;
}
__device__ __forceinline__ unsigned short f2hu(float f) {
  _Float16 h = (_Float16)f;
  return *(unsigned short*)&h;
}
__device__ __forceinline__ half2v ash2(unsigned u) {
  union { unsigned v; half2v h; } x;
  x.v = u;
  return x.h;
}
__device__ __forceinline__ float sigm(float x) {
  return 1.0f / (1.0f + __expf(-x));
}
__device__ __forceinline__ float tanh_f(float x) {
  float e = __expf(2.0f * x);
  return (e - 1.0f) / (e + 1.0f);
}
// flag-dispatched raw load of a "float" input (f32 or bf16 storage)
__device__ __forceinline__ float ldraw(const void* p, size_t i, int f) {
  return f ? ((const float*)p)[i] : bfr2f(((const unsigned short*)p)[i]);
}
// LDS-visibility barrier that does NOT drain vmcnt (keeps global prefetches
// in flight across the sync). sched_barrier fences MIR hoisting (rule #18).
__device__ __forceinline__ void bar_lgkm() {
  asm volatile("s_waitcnt lgkmcnt(0)" ::: "memory");
  __builtin_amdgcn_s_barrier();
  __builtin_amdgcn_sched_barrier(0);
}
// intra-wave LDS write->read fence (no barrier): drain lgkm, pin order.
__device__ __forceinline__ void fence_lgkm() {
  asm volatile("s_waitcnt lgkmcnt(0)" ::: "memory");
  __builtin_amdgcn_sched_barrier(0);
}

// fp16 dot2 (VGPR-class operands; see round 2/3 notes — placement fight is a
// wash, kept for determinism of the emitted dot op).
#define DOTV(acc, ww, hh) \
  asm("v_dot2_f32_f16 %0, %1, %2, %0" : "+v"(acc) : "v"(ww), "v"(hh))

// ---------------------------------------------------------------------------
// Dtype detector (f32 vs bf16 storage of float inputs); see round-2 notes.
__global__ void detect_dtype(const unsigned short* __restrict__ raw,
                             int* __restrict__ flag) {
  __shared__ int cnt[256];
  int c = 0;
  for (int j = 0; j < 32; ++j) {
    unsigned short u = raw[1024 + threadIdx.x * 32 + j];
    int e = (u >> 7) & 0xFF;
    if (e >= 0xC0) ++c;
  }
  cnt[threadIdx.x] = c;
  __syncthreads();
  for (int off = 128; off > 0; off >>= 1) {
    if (threadIdx.x < off) cnt[threadIdx.x] += cnt[threadIdx.x + off];
    __syncthreads();
  }
  if (threadIdx.x == 0) *flag = (cnt[0] > 16) ? 1 : 0;
}

// Zero-fill (uix4 granularity)
__global__ void fill_zero(uix4* __restrict__ p, size_t n4) {
  size_t i = (size_t)blockIdx.x * blockDim.x + threadIdx.x;
  size_t stride = (size_t)gridDim.x * blockDim.x;
  uix4 z = {0u, 0u, 0u, 0u};
  for (; i < n4; i += stride) p[i] = z;
}

// ---------------------------------------------------------------------------
// Embedding concat into X0 [BT][K0P] — reads raw tables (flag-dispatched)
__global__ void embed_kernel(const int* __restrict__ words,
                             const int* __restrict__ pos,
                             const int* __restrict__ ner,
                             const void* __restrict__ emb_w,
                             const void* __restrict__ pos_w,
                             const void* __restrict__ ner_w,
                             __hip_bfloat16* __restrict__ X0,
                             const int* __restrict__ flag) {
  int bt = blockIdx.x;
  int f = *flag;
  int w = words[bt], p = pos[bt], nr = ner[bt];
  for (int j = threadIdx.x; j < K0P; j += blockDim.x) {
    float v;
    if (j < 300)       v = ldraw(emb_w, (size_t)w * 300 + j, f);
    else if (j < 330)  v = ldraw(pos_w, (size_t)p * 30 + (j - 300), f);
    else if (j < 360)  v = ldraw(ner_w, (size_t)nr * 30 + (j - 330), f);
    else               v = 0.0f;
    X0[(size_t)bt * K0P + j] = __float2bfloat16(v);
  }
}

// Pad-copy both directions' W_ih into one stacked [1600][Kp] bf16 matrix
__global__ void pad_copy2(const void* __restrict__ srcf,
                          const void* __restrict__ srcb,
                          __hip_bfloat16* __restrict__ dst, int K, int Kp,
                          const int* __restrict__ flag) {
  int r = blockIdx.x;  // 0..1599
  int f = *flag;
  const void* src = (r < G4) ? srcf : srcb;
  int rr = (r < G4) ? r : r - G4;
  for (int j = threadIdx.x; j < Kp; j += blockDim.x) {
    float v = (j < K) ? ldraw(src, (size_t)rr * K + j, f) : 0.0f;
    dst[(size_t)r * Kp + j] = __float2bfloat16(v);
  }
}

// Pack all 4 W_hh [800][200] into k-pairwise FP16 dwords (fp16 exact for
// bf16-derived weights; enables v_dot2_f32_f16: 1 instr / 2 MACs, f32 acc).
__global__ void pack_whh4(const void* __restrict__ s0, const void* __restrict__ s1,
                          const void* __restrict__ s2, const void* __restrict__ s3,
                          unsigned* __restrict__ dst,
                          const int* __restrict__ flag) {
  int idx = blockIdx.x * blockDim.x + threadIdx.x;  // 4*800*100
  if (idx >= 4 * G4 * 100) return;
  int f = *flag;
  int m = idx / (G4 * 100);
  int loc = idx - m * (G4 * 100);
  const void* src = (m == 0) ? s0 : (m == 1) ? s1 : (m == 2) ? s2 : s3;
  int n = loc / 100, p = loc - n * 100;
  float lo_f = ldraw(src, (size_t)n * 200 + 2 * p, f);
  float hi_f = ldraw(src, (size_t)n * 200 + 2 * p + 1, f);
  dst[idx] = (unsigned)f2hu(lo_f) | ((unsigned)f2hu(hi_f) << 16);
}

// ---------------------------------------------------------------------------
// MFMA GEMM: C[M,N] = A[M,Kp] @ Bm[N,Kp]^T   (bf16 in, fp32 acc, bf16 out)
__global__ __launch_bounds__(256) void gemm_bt(
    const __hip_bfloat16* __restrict__ A,
    const __hip_bfloat16* __restrict__ Bm,
    __hip_bfloat16* __restrict__ C,
    int N, int Kp) {
  const int lane = threadIdx.x & 63;
  const int wave = threadIdx.x >> 6;
  const int l15 = lane & 15, quad = lane >> 4;
  const int m0 = blockIdx.x * 64 + (wave & 1) * 32;
  const int n0 = blockIdx.y * 64 + (wave >> 1) * 32;

  f32x4 acc[2][2] = {};

  int c0 = n0 + l15;       if (c0 > N - 1) c0 = N - 1;
  int c1 = n0 + 16 + l15;  if (c1 > N - 1) c1 = N - 1;
  const size_t ar0 = (size_t)(m0 + l15) * Kp;
  const size_t ar1 = (size_t)(m0 + 16 + l15) * Kp;
  const size_t br0 = (size_t)c0 * Kp;
  const size_t br1 = (size_t)c1 * Kp;

  for (int k0 = 0; k0 < Kp; k0 += 32) {
    int ko = k0 + quad * 8;
    bf16x8 a0 = *(const bf16x8*)(A + ar0 + ko);
    bf16x8 a1 = *(const bf16x8*)(A + ar1 + ko);
    bf16x8 b0 = *(const bf16x8*)(Bm + br0 + ko);
    bf16x8 b1 = *(const bf16x8*)(Bm + br1 + ko);
    acc[0][0] = __builtin_amdgcn_mfma_f32_16x16x32_bf16(a0, b0, acc[0][0], 0, 0, 0);
    acc[0][1] = __builtin_amdgcn_mfma_f32_16x16x32_bf16(a0, b1, acc[0][1], 0, 0, 0);
    acc[1][0] = __builtin_amdgcn_mfma_f32_16x16x32_bf16(a1, b0, acc[1][0], 0, 0, 0);
    acc[1][1] = __builtin_amdgcn_mfma_f32_16x16x32_bf16(a1, b1, acc[1][1], 0, 0, 0);
  }
  #pragma unroll
  for (int mi = 0; mi < 2; ++mi)
    #pragma unroll
    for (int ni = 0; ni < 2; ++ni)
      #pragma unroll
      for (int r = 0; r < 4; ++r) {
        int row = m0 + mi * 16 + quad * 4 + r;
        int col = n0 + ni * 16 + l15;
        if (col < N)
          C[(size_t)row * N + col] = __float2bfloat16(acc[mi][ni][r]);
      }
}

// ---------------------------------------------------------------------------
// LSTM recurrence v10: ONE barrier per step.
// Round-3 analysis: 3536 cyc/step with only ~600-1200 of dot issue — the rest
// was skeleton: 2 barriers + cross-wave hsh LDS round-trip + a reduce phase
// run by 200/512 threads while 6/8 waves idled at barrier 2. Restructure:
//  - redundant reduce on ALL 8 waves: wave kq computes exactly the h-quarter
//    [50*kq, 50*kq+50) that it consumes (lanes 0..49, one unit each). Wave
//    pairs (kq, kq+4) duplicate the computation (bit-identical, same inputs).
//  - wave-private hshW[8][64]: each wave writes its 50 hn and reads them back
//    itself -> intra-wave lgkmcnt fence replaces barrier 2 entirely.
//  - parts double-buffered by step parity -> the single remaining barrier
//    (parts visibility) is race-free; max skew is one barrier interval.
//  - out/final_h stores deduped to waves 0..3; Gpre prefetch per-wave
//    (duplicate loads absorbed by L2).
__global__ __launch_bounds__(512, 2) void lstm_row(
    const __hip_bfloat16* __restrict__ Gpre,   // [B*T][1600]  x@W_ih^T (no bias)
    const unsigned* __restrict__ Wpack,        // [2][800][100] packed fp16 k-pairs
    const void* __restrict__ bias_f_raw,       // [800] raw
    const void* __restrict__ bias_b_raw,       // [800] raw
    const int* __restrict__ masks,             // [B][T], 1 = pad
    __hip_bfloat16* __restrict__ out,          // [B][T][ostride] (pre-zeroed)
    int ostride,
    float* __restrict__ final_h,               // [B][400] = [hb | hf], or nullptr
    const int* __restrict__ flag)
{
  const int tid = threadIdx.x;
  const int dir = blockIdx.x >> 7;
  const int row = blockIdx.x & 127;
  const int wave = tid >> 6;
  const int lane = tid & 63;
  const int kq = wave & 3;                    // k-quarter, wave-uniform
  const int gs = ((wave >> 2) << 6) | lane;   // 0..127
  const bool tail = (gs >= 96);               // handles gates 768..799

  __shared__ __align__(16) _Float16 hshW[8][64];  // per-wave h quarter, 1 KB
  __shared__ float parts[2][4 * 804];             // dbuf by step parity, 25728 B
  __shared__ int lensh[256];                      // length reduce scratch
  __shared__ int bigbuf[21504];                   // 86016 B: [0:3232)=tail W
                                                  // (stride 101); rest pads LDS
                                                  // >80KB so 1 block/CU

  const unsigned* wb = Wpack + (size_t)dir * G4 * 100;

  // --- stage tail-gate weights (768..799), stride 101 ---
  for (int i = tid; i < 3200; i += 512) {
    int g = i / 100, c = i - g * 100;
    bigbuf[g * 101 + c] = (int)wb[(768 + g) * 100 + c];
  }
  // --- per-row length: count of keep tokens (pads are a contiguous tail) ---
  if (tid < 256) lensh[tid] = (masks[row * T + tid] == 0) ? 1 : 0;

  // --- register weights: 150 dwords/thread, compile-time indices ---
  unsigned w[6][25];
  {
    const unsigned* s = wb + gs * 100 + kq * 25;
    #pragma unroll
    for (int j = 0; j < 6; ++j)
      #pragma unroll
      for (int p = 0; p < 25; ++p)
        w[j][p] = s[12800 * j + p];
  }
  const unsigned* wt = (const unsigned*)&bigbuf[(gs - 96) * 101 + kq * 25];

  // --- reduce-lane constants: unit ul = 50*kq + lane (lanes 0..49) ---
  const bool red = (lane < 50);
  const int ul = 50 * kq + lane;
  const int f = *flag;
  const void* braw = dir ? bias_b_raw : bias_f_raw;
  float bI = 0.f, bF = 0.f, bG = 0.f, bO = 0.f;
  if (red) {
    bI = ldraw(braw, ul, f);
    bF = ldraw(braw, 200 + ul, f);
    bG = ldraw(braw, 400 + ul, f);
    bO = ldraw(braw, 600 + ul, f);
  }

  hshW[wave][lane] = (_Float16)0.0f;   // zero own slot incl. pad halfs
  float creg = 0.0f, hreg = 0.0f;
  __syncthreads();

  // --- length tree-reduce ---
  for (int off = 128; off > 0; off >>= 1) {
    if (tid < off) lensh[tid] += lensh[tid + off];
    __syncthreads();
  }
  const int len = lensh[0];   // in [128, 256]

  const unsigned short* gp = (const unsigned short*)Gpre + dir * 800;
  const size_t gbase = (size_t)row * T;
  const uix4* hvp = (const uix4*)hshW[wave];   // 128 B per wave, 16B aligned

  // --- prologue: gate loads for step 0 ---
  unsigned short qI = 0, qF = 0, qG = 0, qO = 0;
  {
    const int t0 = dir ? (len - 1) : 0;
    const size_t g0 = (gbase + t0) * 1600;
    if (red) {
      qI = gp[g0 + ul];
      qF = gp[g0 + 200 + ul];
      qG = gp[g0 + 400 + ul];
      qO = gp[g0 + 600 + ul];
    }
  }

  #pragma unroll 1
  for (int tt = 0; tt < len; ++tt) {
    const int t = dir ? (len - 1 - tt) : tt;

    // --- prefetch next step's gate pre-activations (consumed next iter) ---
    int tn = dir ? (len - 2 - tt) : (tt + 1);
    if (tn < 0) tn = 0;
    if (tn > T - 1) tn = T - 1;
    unsigned short nI = 0, nF = 0, nG = 0, nO = 0;
    if (red) {
      const size_t gn = (gbase + tn) * 1600;
      nI = gp[gn + ul];
      nF = gp[gn + 200 + ul];
      nG = gp[gn + 400 + ul];
      nO = gp[gn + 600 + ul];
    }

    // --- dot phase: wave-private h broadcast reads + fp16 dot2 ---
    float a0 = 0.f, a1 = 0.f, a2 = 0.f, a3 = 0.f, a4 = 0.f, a5 = 0.f;
    uix4 hb[7];
    #pragma unroll
    for (int ci = 0; ci < 7; ++ci) {
      hb[ci] = hvp[ci];
      const int np = (ci < 6) ? 4 : 1;
      #pragma unroll
      for (int j = 0; j < np; ++j) {
        const int p = ci * 4 + j;
        unsigned hv = hb[ci][j];
        DOTV(a0, w[0][p], hv);
        DOTV(a1, w[1][p], hv);
        DOTV(a2, w[2][p], hv);
        DOTV(a3, w[3][p], hv);
        DOTV(a4, w[4][p], hv);
        DOTV(a5, w[5][p], hv);
      }
    }
    float* pb = &parts[tt & 1][kq * 804];
    pb[gs]        = a0;
    pb[128 + gs]  = a1;
    pb[256 + gs]  = a2;
    pb[384 + gs]  = a3;
    pb[512 + gs]  = a4;
    pb[640 + gs]  = a5;
    if (tail) {
      float a6 = 0.f;
      #pragma unroll
      for (int p = 0; p < 25; ++p) {
        unsigned wv = wt[p];
        unsigned hv = hb[p >> 2][p & 3];
        DOTV(a6, wv, hv);
      }
      pb[672 + gs] = a6;   // slot == gate 768+(gs-96)
    }
    bar_lgkm();   // THE barrier: parts[tt&1] visible to all waves

    // --- reduce + nonlinearity: all 8 waves, lanes 0..49, 1 unit each ---
    if (red) {
      const float* pr = parts[tt & 1];
      float gi = pr[ul]        + pr[804 + ul]        + pr[1608 + ul]        + pr[2412 + ul]        + bI + bfr2f(qI);
      float gf = pr[200 + ul]  + pr[804 + 200 + ul]  + pr[1608 + 200 + ul]  + pr[2412 + 200 + ul]  + bF + bfr2f(qF);
      float gg = pr[400 + ul]  + pr[804 + 400 + ul]  + pr[1608 + 400 + ul]  + pr[2412 + 400 + ul]  + bG + bfr2f(qG);
      float go = pr[600 + ul]  + pr[804 + 600 + ul]  + pr[1608 + 600 + ul]  + pr[2412 + 600 + ul]  + bO + bfr2f(qO);
      float si = sigm(gi), sf = sigm(gf), so = sigm(go);
      float cn = sf * creg + si * tanh_f(gg);
      float hn = so * tanh_f(cn);
      creg = cn;
      hreg = hn;
      hshW[wave][lane] = (_Float16)hn;     // wave-private: consumed by self
      if (wave < 4)                        // dedup global store
        out[((size_t)row * T + t) * ostride + dir * H + ul] = __float2bfloat16(hn);
    }
    fence_lgkm();   // intra-wave: hshW write visible to own wave's next dot

    qI = nI; qF = nF; qG = nG; qO = nO;
  }

  if (final_h != nullptr && wave < 4 && red) {
    // glob_h = [hb1 | hf1]: backward dir -> cols 0..199, forward -> 200..399
    int col = dir ? ul : (H + ul);
    final_h[(size_t)row * 400 + col] = hreg;
  }
}

// ---------------------------------------------------------------------------
// Span sums v2: chunked (t-chunk x d-octet) with bf16x8 row loads.
// Threads: tc = tid>>6 (t-chunk of 64), dv = tid&63 (d-octet, active < 50).
// Flag loads are wave-uniform (scalar); rows loaded only on span hits.
__global__ __launch_bounds__(256) void span_sum(
    const __hip_bfloat16* __restrict__ rnn,   // [B][T][400]
    const int* __restrict__ masks,
    const int* __restrict__ subj_pos,
    const int* __restrict__ obj_pos,
    float* __restrict__ obj_h,   // [B][400]
    float* __restrict__ subj_h)  // [B][400]
{
  int b = blockIdx.x;
  int tc = threadIdx.x >> 6;
  int dv = threadIdx.x & 63;
  __shared__ float aS[4][400];
  __shared__ float aO[4][400];

  float ss[8] = {}, so[8] = {};
  if (dv < 50) {
    for (int t = tc * 64; t < tc * 64 + 64; ++t) {
      int m = masks[b * T + t];
      int fs = (subj_pos[b * T + t] + m) == 0;
      int fo = (obj_pos[b * T + t] + m) == 0;
      if (fs | fo) {
        uix4 v = *(const uix4*)(rnn + ((size_t)b * T + t) * 400 + dv * 8);
        #pragma unroll
        for (int j = 0; j < 4; ++j) {
          float lo = bfr2f((unsigned short)(v[j] & 0xFFFF));
          float hi = bfr2f((unsigned short)(v[j] >> 16));
          if (fs) { ss[2 * j] += lo; ss[2 * j + 1] += hi; }
          if (fo) { so[2 * j] += lo; so[2 * j + 1] += hi; }
        }
      }
    }
    #pragma unroll
    for (int k = 0; k < 8; ++k) {
      aS[tc][dv * 8 + k] = ss[k];
      aO[tc][dv * 8 + k] = so[k];
    }
  }
  __syncthreads();
  for (int d = threadIdx.x; d < 400; d += 256) {
    subj_h[(size_t)b * 400 + d] = aS[0][d] + aS[1][d] + aS[2][d] + aS[3][d];
    obj_h[(size_t)b * 400 + d]  = aO[0][d] + aO[1][d] + aO[2][d] + aO[3][d];
  }
}

// ---------------------------------------------------------------------------
// Single-query attention pooling v2. grid = 3*128 (qi = blk>>7, b = blk&127).
// Phase 1 vectorized to bf16x8 row loads; phase 2 restructured to chunked
// (t-chunk x d-octet) coalesced loads + LDS 4-way combine. Pad steps skip
// wave-uniformly (ps == 0 exactly: exp(-1e9 - mx) underflows).
__global__ __launch_bounds__(256) void attn_pool_k(
    const float* __restrict__ qbuf,           // [3][B][400]
    const __hip_bfloat16* __restrict__ rnn,   // [B][T][400]
    const int* __restrict__ masks,
    float* __restrict__ outp)                 // [3][B][400]
{
  int b = blockIdx.x & 127;
  int qi = blockIdx.x >> 7;
  __shared__ float qs[400];
  __shared__ float ps[256];
  __shared__ float red[256];
  __shared__ float acc4[4][400];
  const float* q = qbuf + ((size_t)qi * B + b) * 400;
  for (int d = threadIdx.x; d < 400; d += 256) qs[d] = q[d];
  __syncthreads();

  int t = threadIdx.x;
  const uix4* kvv = (const uix4*)(rnn + ((size_t)b * T + t) * 400);
  float s = 0.f;
  #pragma unroll 5
  for (int i = 0; i < 50; ++i) {
    uix4 v = kvv[i];
    #pragma unroll
    for (int j = 0; j < 4; ++j) {
      s += bfr2f((unsigned short)(v[j] & 0xFFFF)) * qs[8 * i + 2 * j];
      s += bfr2f((unsigned short)(v[j] >> 16))    * qs[8 * i + 2 * j + 1];
    }
  }
  s *= 0.05f;  // 1/sqrt(400)
  if (masks[b * T + t] != 0) s = -1e9f;

  red[t] = s;
  __syncthreads();
  for (int off = 128; off > 0; off >>= 1) {
    if (t < off) red[t] = fmaxf(red[t], red[t + off]);
    __syncthreads();
  }
  float mx = red[0];
  __syncthreads();
  float e = expf(s - mx);
  red[t] = e;
  __syncthreads();
  for (int off = 128; off > 0; off >>= 1) {
    if (t < off) red[t] += red[t + off];
    __syncthreads();
  }
  float inv = 1.0f / red[0];
  ps[t] = e * inv;
  __syncthreads();

  // --- phase 2: out[d] = sum_t ps[t] * rnn[t][d], chunked ---
  int tc = threadIdx.x >> 6;
  int dv = threadIdx.x & 63;
  float a[8] = {};
  if (dv < 50) {
    for (int t2 = tc * 64; t2 < tc * 64 + 64; ++t2) {
      float wgt = ps[t2];              // wave-uniform (LDS broadcast)
      if (wgt != 0.f) {
        uix4 v = *(const uix4*)(rnn + ((size_t)b * T + t2) * 400 + dv * 8);
        #pragma unroll
        for (int j = 0; j < 4; ++j) {
          a[2 * j]     += wgt * bfr2f((unsigned short)(v[j] & 0xFFFF));
          a[2 * j + 1] += wgt * bfr2f((unsigned short)(v[j] >> 16));
        }
      }
    }
    #pragma unroll
    for (int k = 0; k < 8; ++k) acc4[tc][dv * 8 + k] = a[k];
  }
  __syncthreads();
  for (int d = threadIdx.x; d < 400; d += 256)
    outp[((size_t)qi * B + b) * 400 + d] =
        acc4[0][d] + acc4[1][d] + acc4[2][d] + acc4[3][d];
}

// ---------------------------------------------------------------------------
// Head — reads all weights raw (flag-dispatched), writes bf16 or f32 per flag
__global__ __launch_bounds__(256) void final_head(
    const float* __restrict__ attn,   // [3][B][400]: 0=obj,1=subj,2=glob
    const void* __restrict__ wo_w, const void* __restrict__ wo_b,
    const void* __restrict__ ws_w, const void* __restrict__ ws_b,
    const void* __restrict__ wg_w, const void* __restrict__ wg_b,
    const void* __restrict__ cls_w, const void* __restrict__ cls_b,
    void* __restrict__ outp,          // [B][2]
    const int* __restrict__ flag)
{
  int b = blockIdx.x;
  int f = *flag;
  __shared__ float hs[H];
  int j = threadIdx.x;
  if (j < H) {
    float acc = ldraw(wo_b, j, f) + ldraw(ws_b, j, f) + ldraw(wg_b, j, f);
    const float* oa = attn + ((size_t)0 * B + b) * 400;
    const float* sa = attn + ((size_t)1 * B + b) * 400;
    const float* ga = attn + ((size_t)2 * B + b) * 400;
    for (int d = 0; d < 400; ++d) {
      acc += oa[d] * ldraw(wo_w, (size_t)j * 400 + d, f);
      acc += sa[d] * ldraw(ws_w, (size_t)j * 400 + d, f);
      acc += ga[d] * ldraw(wg_w, (size_t)j * 400 + d, f);
    }
    hs[j] = fmaxf(acc, 0.0f);
  }
  __syncthreads();
  if (j < 2) {
    float a = ldraw(cls_b, j, f);
    for (int k = 0; k < H; ++k)
      a += hs[k] * ldraw(cls_w, (size_t)j * H + k, f);
    if (f) ((float*)outp)[b * 2 + j] = a;
    else   ((__hip_bfloat16*)outp)[b * 2 + j] = __float2bfloat16(a);
  }
}

// ---------------------------------------------------------------------------
// Workspace layout (bytes)
constexpr size_t O_X0   = 0;            // 32768*384*2  = 25165824
constexpr size_t O_X1   = 25165824;     // 32768*416*2  = 27262976
constexpr size_t O_GPRE = 52428800;     // 32768*1600*2 = 104857600
constexpr size_t O_RNN  = 157286400;    // 32768*400*2  = 26214400
constexpr size_t O_WIH0 = 183500800;    // 1600*384*2   = 1228800
constexpr size_t O_WIH1 = 184729600;    // 1600*416*2   = 1331200
constexpr size_t O_WPK  = 186060800;    // 4*800*100*4  = 1280000
constexpr size_t O_Q    = 187340800;    // 3*128*400*4  = 614400
constexpr size_t O_ATT  = 187955200;    // 614400
constexpr size_t O_FLAG = 188569600;    // 256

extern "C" void kernel_launch(void* const* d_in, const int* in_sizes, int n_in,
                              void* d_out, int out_size, void* d_ws, size_t ws_size,
                              hipStream_t stream) {
  (void)in_sizes; (void)n_in; (void)out_size; (void)ws_size;

  const int* words = (const int*)d_in[0];
  const int* masks = (const int*)d_in[1];
  const int* pos   = (const int*)d_in[2];
  const int* ner   = (const int*)d_in[3];
  const int* subj  = (const int*)d_in[4];
  const int* obj   = (const int*)d_in[5];
  const void* emb_w = d_in[6];
  const void* pos_w = d_in[7];
  const void* ner_w = d_in[8];
  const void* wih[4]  = {d_in[9],  d_in[12], d_in[15], d_in[18]};
  const void* whh[4]  = {d_in[10], d_in[13], d_in[16], d_in[19]};
  const void* bias[4] = {d_in[11], d_in[14], d_in[17], d_in[20]};
  const void* wo_w = d_in[21]; const void* wo_b = d_in[22];
  const void* ws_w = d_in[23]; const void* ws_b = d_in[24];
  const void* wg_w = d_in[25]; const void* wg_b = d_in[26];
  const void* cls_w = d_in[27]; const void* cls_b = d_in[28];

  char* ws = (char*)d_ws;
  __hip_bfloat16* X0   = (__hip_bfloat16*)(ws + O_X0);
  __hip_bfloat16* X1   = (__hip_bfloat16*)(ws + O_X1);
  __hip_bfloat16* Gpre = (__hip_bfloat16*)(ws + O_GPRE);   // [BT][1600]
  __hip_bfloat16* RNN  = (__hip_bfloat16*)(ws + O_RNN);
  __hip_bfloat16* wih0p = (__hip_bfloat16*)(ws + O_WIH0);  // [1600][384]
  __hip_bfloat16* wih1p = (__hip_bfloat16*)(ws + O_WIH1);  // [1600][416]
  unsigned* Wpack = (unsigned*)(ws + O_WPK);               // [4][800][100]
  float* qbuf = (float*)(ws + O_Q);    // [3][B][400]: obj, subj, glob
  float* attb = (float*)(ws + O_ATT);  // [3][B][400]
  int* flag = (int*)(ws + O_FLAG);

  // --- dtype detect + weight prep (all read raw, flag-dispatched) ---
  detect_dtype<<<1, 256, 0, stream>>>((const unsigned short*)emb_w, flag);
  pack_whh4<<<1250, 256, 0, stream>>>(whh[0], whh[1], whh[2], whh[3], Wpack, flag);
  pad_copy2<<<1600, 128, 0, stream>>>(wih[0], wih[1], wih0p, K0, K0P, flag);
  pad_copy2<<<1600, 128, 0, stream>>>(wih[2], wih[3], wih1p, K1, K1P, flag);

  // --- embedding + output-buffer zero fills (lstm skips padded steps) ---
  embed_kernel<<<BT, 128, 0, stream>>>(words, pos, ner, emb_w, pos_w, ner_w, X0, flag);
  fill_zero<<<1024, 256, 0, stream>>>((uix4*)X1, (size_t)BT * K1P * 2 / 16);
  fill_zero<<<1024, 256, 0, stream>>>((uix4*)RNN, (size_t)BT * 400 * 2 / 16);

  dim3 ggrid(BT / 64, 25);  // N = 1600 (both dirs fused)

  // --- layer 0 ---
  gemm_bt<<<ggrid, 256, 0, stream>>>(X0, wih0p, Gpre, 1600, K0P);
  lstm_row<<<256, 512, 0, stream>>>(Gpre, Wpack, bias[0], bias[1], masks,
                                    X1, K1P, nullptr, flag);

  // --- layer 1 ---
  gemm_bt<<<ggrid, 256, 0, stream>>>(X1, wih1p, Gpre, 1600, K1P);
  float* qglob = qbuf + (size_t)2 * B * 400;
  lstm_row<<<256, 512, 0, stream>>>(Gpre, Wpack + (size_t)2 * G4 * 100,
                                    bias[2], bias[3], masks,
                                    RNN, 400, qglob, flag);

  // --- span sums (obj -> slot0, subj -> slot1) ---
  span_sum<<<B, 256, 0, stream>>>(RNN, masks, subj, obj,
                                  qbuf, qbuf + (size_t)B * 400);

  // --- attention pooling (3 queries) ---
  attn_pool_k<<<3 * B, 256, 0, stream>>>(qbuf, RNN, masks, attb);

  // --- head (raw weights) ---
  final_head<<<B, 256, 0, stream>>>(attb, wo_w, wo_b, ws_w, ws_b, wg_w, wg_b,
                                    cls_w, cls_b, d_out, flag);
}

// Round 7
// 1384.818 us; speedup vs baseline: 1.1434x; 1.1434x over previous
//
#include <hip/hip_runtime.h>
#include <hip/hip_bf16.h>
#include <math.h>

// Problem constants
constexpr int B = 128;
constexpr int T = 256;
constexpr int H = 200;       // hidden
constexpr int G4 = 800;      // 4*H
constexpr int BT = B * T;    // 32768
constexpr int K0 = 360, K0P = 384;   // layer0 input dim, padded to %32
constexpr int K1 = 400, K1P = 416;   // layer1 input dim, padded to %32

typedef __bf16 bf16x8 __attribute__((ext_vector_type(8)));
typedef float f32x4 __attribute__((ext_vector_type(4)));
typedef _Float16 half2v __attribute__((ext_vector_type(2)));
typedef unsigned uix4 __attribute__((ext_vector_type(4)));

__device__ __forceinline__ float bfr2f(unsigned short u) {
  union { unsigned int i; float f; } x;
  x.i = ((unsigned int)u) << 16;
  return x.f;
}
__device__ __forceinline__ unsigned short f2hu(float f) {
  _Float16 h = (_Float16)f;
  return *(unsigned short*)&h;
}
__device__ __forceinline__ half2v ash2(unsigned u) {
  union { unsigned v; half2v h; } x;
  x.v = u;
  return x.h;
}
__device__ __forceinline__ float sigm(float x) {
  return 1.0f / (1.0f + __expf(-x));
}
__device__ __forceinline__ float tanh_f(float x) {
  float e = __expf(2.0f * x);
  return (e - 1.0f) / (e + 1.0f);
}
// flag-dispatched raw load of a "float" input (f32 or bf16 storage)
__device__ __forceinline__ float ldraw(const void* p, size_t i, int f) {
  return f ? ((const float*)p)[i] : bfr2f(((const unsigned short*)p)[i]);
}

// ---------------------------------------------------------------------------
// Dtype detector (f32 vs bf16 storage of float inputs); see round-2 notes.
__global__ void detect_dtype(const unsigned short* __restrict__ raw,
                             int* __restrict__ flag) {
  __shared__ int cnt[256];
  int c = 0;
  for (int j = 0; j < 32; ++j) {
    unsigned short u = raw[1024 + threadIdx.x * 32 + j];
    int e = (u >> 7) & 0xFF;
    if (e >= 0xC0) ++c;
  }
  cnt[threadIdx.x] = c;
  __syncthreads();
  for (int off = 128; off > 0; off >>= 1) {
    if (threadIdx.x < off) cnt[threadIdx.x] += cnt[threadIdx.x + off];
    __syncthreads();
  }
  if (threadIdx.x == 0) *flag = (cnt[0] > 16) ? 1 : 0;
}

// Zero-fill (uix4 granularity)
__global__ void fill_zero(uix4* __restrict__ p, size_t n4) {
  size_t i = (size_t)blockIdx.x * blockDim.x + threadIdx.x;
  size_t stride = (size_t)gridDim.x * blockDim.x;
  uix4 z = {0u, 0u, 0u, 0u};
  for (; i < n4; i += stride) p[i] = z;
}

// ---------------------------------------------------------------------------
// Embedding concat into X0 [BT][K0P] — reads raw tables (flag-dispatched)
__global__ void embed_kernel(const int* __restrict__ words,
                             const int* __restrict__ pos,
                             const int* __restrict__ ner,
                             const void* __restrict__ emb_w,
                             const void* __restrict__ pos_w,
                             const void* __restrict__ ner_w,
                             __hip_bfloat16* __restrict__ X0,
                             const int* __restrict__ flag) {
  int bt = blockIdx.x;
  int f = *flag;
  int w = words[bt], p = pos[bt], nr = ner[bt];
  for (int j = threadIdx.x; j < K0P; j += blockDim.x) {
    float v;
    if (j < 300)       v = ldraw(emb_w, (size_t)w * 300 + j, f);
    else if (j < 330)  v = ldraw(pos_w, (size_t)p * 30 + (j - 300), f);
    else if (j < 360)  v = ldraw(ner_w, (size_t)nr * 30 + (j - 330), f);
    else               v = 0.0f;
    X0[(size_t)bt * K0P + j] = __float2bfloat16(v);
  }
}

// Pad-copy both directions' W_ih into one stacked [1600][Kp] bf16 matrix
__global__ void pad_copy2(const void* __restrict__ srcf,
                          const void* __restrict__ srcb,
                          __hip_bfloat16* __restrict__ dst, int K, int Kp,
                          const int* __restrict__ flag) {
  int r = blockIdx.x;  // 0..1599
  int f = *flag;
  const void* src = (r < G4) ? srcf : srcb;
  int rr = (r < G4) ? r : r - G4;
  for (int j = threadIdx.x; j < Kp; j += blockDim.x) {
    float v = (j < K) ? ldraw(src, (size_t)rr * K + j, f) : 0.0f;
    dst[(size_t)r * Kp + j] = __float2bfloat16(v);
  }
}

// Pack all 4 W_hh [800][200] into k-pairwise FP16 dwords (fp16 exact for
// bf16-derived weights; enables v_dot2_f32_f16: 1 instr / 2 MACs, f32 acc).
__global__ void pack_whh4(const void* __restrict__ s0, const void* __restrict__ s1,
                          const void* __restrict__ s2, const void* __restrict__ s3,
                          unsigned* __restrict__ dst,
                          const int* __restrict__ flag) {
  int idx = blockIdx.x * blockDim.x + threadIdx.x;  // 4*800*100
  if (idx >= 4 * G4 * 100) return;
  int f = *flag;
  int m = idx / (G4 * 100);
  int loc = idx - m * (G4 * 100);
  const void* src = (m == 0) ? s0 : (m == 1) ? s1 : (m == 2) ? s2 : s3;
  int n = loc / 100, p = loc - n * 100;
  float lo_f = ldraw(src, (size_t)n * 200 + 2 * p, f);
  float hi_f = ldraw(src, (size_t)n * 200 + 2 * p + 1, f);
  dst[idx] = (unsigned)f2hu(lo_f) | ((unsigned)f2hu(hi_f) << 16);
}

// ---------------------------------------------------------------------------
// MFMA GEMM v2: C[M,N] = A[M,Kp] @ Bm[N,Kp]^T (bf16 in, fp32 acc, bf16 out).
// Widened per-wave tile 32x32 -> 32x64 (acc 2x4): the verified 2x2 version
// issued 4 global loads per 4 MFMAs (ratio 1.0); sharing each a0/a1 pair
// across 4 B-columns gives 6 loads per 8 MFMAs (0.75) and halves per-MFMA
// address VALU. Block tile 64x128, grid (BT/64, ceil(N/128)). Fragment
// mapping identical to the verified kernel.
__global__ __launch_bounds__(256) void gemm_bt(
    const __hip_bfloat16* __restrict__ A,
    const __hip_bfloat16* __restrict__ Bm,
    __hip_bfloat16* __restrict__ C,
    int N, int Kp) {
  const int lane = threadIdx.x & 63;
  const int wave = threadIdx.x >> 6;
  const int l15 = lane & 15, quad = lane >> 4;
  const int m0 = blockIdx.x * 64 + (wave & 1) * 32;
  const int n0 = blockIdx.y * 128 + (wave >> 1) * 64;

  f32x4 acc[2][4] = {};

  size_t br[4];
  #pragma unroll
  for (int j = 0; j < 4; ++j) {
    int c = n0 + 16 * j + l15;
    if (c > N - 1) c = N - 1;   // clamped read; store is guarded by col<N
    br[j] = (size_t)c * Kp;
  }
  const size_t ar0 = (size_t)(m0 + l15) * Kp;
  const size_t ar1 = (size_t)(m0 + 16 + l15) * Kp;

  for (int k0 = 0; k0 < Kp; k0 += 32) {
    int ko = k0 + quad * 8;
    bf16x8 a0 = *(const bf16x8*)(A + ar0 + ko);
    bf16x8 a1 = *(const bf16x8*)(A + ar1 + ko);
    #pragma unroll
    for (int j = 0; j < 4; ++j) {
      bf16x8 b = *(const bf16x8*)(Bm + br[j] + ko);
      acc[0][j] = __builtin_amdgcn_mfma_f32_16x16x32_bf16(a0, b, acc[0][j], 0, 0, 0);
      acc[1][j] = __builtin_amdgcn_mfma_f32_16x16x32_bf16(a1, b, acc[1][j], 0, 0, 0);
    }
  }
  #pragma unroll
  for (int mi = 0; mi < 2; ++mi)
    #pragma unroll
    for (int ni = 0; ni < 4; ++ni)
      #pragma unroll
      for (int r = 0; r < 4; ++r) {
        int row = m0 + mi * 16 + quad * 4 + r;
        int col = n0 + ni * 16 + l15;
        if (col < N)
          C[(size_t)row * N + col] = __float2bfloat16(acc[mi][ni][r]);
      }
}

// ---------------------------------------------------------------------------
// LSTM recurrence v7 (verbatim from round 1, best verified: 360 µs/dispatch).
// 512 threads / 8 waves / 2 waves per SIMD; 4-way k-split kq=wave&3 (h reads
// are wave-uniform LDS broadcasts); gs in [0,128) owns 6 gates x 25 k-pairs
// = 150 weight dwords; tail gates 768..799 from LDS (stride 101).
// NOTE (rounds 2-4): prefetch / counted-vmcnt barriers / asm dot / 1-barrier
// restructures were all neutral-to-negative; the 1024-thread geometry (v11)
// is untested due to two container-level bench failures — this round is a
// known-good canary to disambiguate infra vs kernel.
__global__ __launch_bounds__(512, 2) void lstm_row(
    const __hip_bfloat16* __restrict__ Gpre,   // [B*T][1600]  x@W_ih^T (no bias)
    const unsigned* __restrict__ Wpack,        // [2][800][100] packed fp16 k-pairs
    const void* __restrict__ bias_f_raw,       // [800] raw
    const void* __restrict__ bias_b_raw,       // [800] raw
    const int* __restrict__ masks,             // [B][T], 1 = pad
    __hip_bfloat16* __restrict__ out,          // [B][T][ostride] (pre-zeroed)
    int ostride,
    float* __restrict__ final_h,               // [B][400] = [hb | hf], or nullptr
    const int* __restrict__ flag)
{
  const int tid = threadIdx.x;
  const int dir = blockIdx.x >> 7;
  const int row = blockIdx.x & 127;
  const int wave = tid >> 6;
  const int lane = tid & 63;
  const int kq = wave & 3;                    // k-quarter, wave-uniform
  const int gs = ((wave >> 2) << 6) | lane;   // 0..127
  const bool tail = (gs >= 96);               // handles gates 768..799

  __shared__ __align__(16) _Float16 hsh[256];  // 4 quarters x 64 halfs
  __shared__ float parts[4 * 804];             // [kq][gate(+4)], 12864 B
  __shared__ int lensh[256];                   // length reduce scratch
  __shared__ int bigbuf[21504];                // 86016 B: [0:3232)=tail W
                                               // (stride 101); rest pads LDS
                                               // >80KB so 1 block/CU

  const unsigned* wb = Wpack + (size_t)dir * G4 * 100;

  // --- stage tail-gate weights (768..799), stride 101 ---
  for (int i = tid; i < 3200; i += 512) {
    int g = i / 100, c = i - g * 100;
    bigbuf[g * 101 + c] = (int)wb[(768 + g) * 100 + c];
  }
  // --- per-row length: count of keep tokens (pads are a contiguous tail) ---
  if (tid < 256) lensh[tid] = (masks[row * T + tid] == 0) ? 1 : 0;

  // --- register weights: 150 dwords/thread, compile-time indices ---
  unsigned w[6][25];
  {
    const unsigned* s = wb + gs * 100 + kq * 25;
    #pragma unroll
    for (int j = 0; j < 6; ++j)
      #pragma unroll
      for (int p = 0; p < 25; ++p)
        w[j][p] = s[12800 * j + p];
  }
  const unsigned* wt = (const unsigned*)&bigbuf[(gs - 96) * 101 + kq * 25];

  // --- reduce-thread constants (u = hidden unit) ---
  const int u = tid;
  const int f = *flag;
  const void* braw = dir ? bias_b_raw : bias_f_raw;
  float bI = 0.f, bF = 0.f, bG = 0.f, bO = 0.f;
  if (u < 200) {
    bI = ldraw(braw, u, f);
    bF = ldraw(braw, 200 + u, f);
    bG = ldraw(braw, 400 + u, f);
    bO = ldraw(braw, 600 + u, f);
  }

  if (tid < 256) hsh[tid] = (_Float16)0.0f;   // zero all quarters incl. pads
  float creg = 0.0f, hreg = 0.0f;
  __syncthreads();

  // --- length tree-reduce ---
  for (int off = 128; off > 0; off >>= 1) {
    if (tid < off) lensh[tid] += lensh[tid + off];
    __syncthreads();
  }
  const int len = lensh[0];   // in [128, 256]

  const unsigned short* gp = (const unsigned short*)Gpre + dir * 800;
  const size_t gbase = (size_t)row * T;
  const uix4* hvp = (const uix4*)((const char*)hsh + kq * 128);
  const int hwrite = (u / 50) * 64 + (u % 50);  // quarter-padded h index

  #pragma unroll 1
  for (int tt = 0; tt < len; ++tt) {
    const int t = dir ? (len - 1 - tt) : tt;
    const size_t goff = (gbase + t) * 1600;
    // prefetch gate pre-activations (consumed in the reduce phase)
    unsigned short qI = 0, qF = 0, qG = 0, qO = 0;
    if (u < 200) {
      qI = gp[goff + u];
      qF = gp[goff + 200 + u];
      qG = gp[goff + 400 + u];
      qO = gp[goff + 600 + u];
    }

    // --- h plane: 7 broadcast b128 reads of this k-quarter ---
    uix4 hb[7];
    #pragma unroll
    for (int i = 0; i < 7; ++i) hb[i] = hvp[i];

    // --- dot phase: fp16 dot2, f32 accumulate ---
    float a0 = 0.f, a1 = 0.f, a2 = 0.f, a3 = 0.f, a4 = 0.f, a5 = 0.f;
    #pragma unroll
    for (int p = 0; p < 25; ++p) {
      half2v h2 = ash2(hb[p >> 2][p & 3]);
      a0 = __builtin_amdgcn_fdot2(ash2(w[0][p]), h2, a0, false);
      a1 = __builtin_amdgcn_fdot2(ash2(w[1][p]), h2, a1, false);
      a2 = __builtin_amdgcn_fdot2(ash2(w[2][p]), h2, a2, false);
      a3 = __builtin_amdgcn_fdot2(ash2(w[3][p]), h2, a3, false);
      a4 = __builtin_amdgcn_fdot2(ash2(w[4][p]), h2, a4, false);
      a5 = __builtin_amdgcn_fdot2(ash2(w[5][p]), h2, a5, false);
    }
    const int pb = kq * 804;
    parts[pb + gs]        = a0;
    parts[pb + 128 + gs]  = a1;
    parts[pb + 256 + gs]  = a2;
    parts[pb + 384 + gs]  = a3;
    parts[pb + 512 + gs]  = a4;
    parts[pb + 640 + gs]  = a5;
    if (tail) {
      float a6 = 0.f;
      #pragma unroll
      for (int p = 0; p < 25; ++p)
        a6 = __builtin_amdgcn_fdot2(ash2(wt[p]), ash2(hb[p >> 2][p & 3]), a6, false);
      parts[pb + 672 + gs] = a6;   // gate 768+(gs-96)
    }
    __syncthreads();

    // --- reduce + nonlinearity (threads 0..199); no pads inside [0,len) ---
    if (u < 200) {
      float gi = parts[u]       + parts[804 + u]       + parts[1608 + u]       + parts[2412 + u]       + bI + bfr2f(qI);
      float gf = parts[200 + u] + parts[804 + 200 + u] + parts[1608 + 200 + u] + parts[2412 + 200 + u] + bF + bfr2f(qF);
      float gg = parts[400 + u] + parts[804 + 400 + u] + parts[1608 + 400 + u] + parts[2412 + 400 + u] + bG + bfr2f(qG);
      float go = parts[600 + u] + parts[804 + 600 + u] + parts[1608 + 600 + u] + parts[2412 + 600 + u] + bO + bfr2f(qO);
      float si = sigm(gi), sf = sigm(gf), so = sigm(go);
      float cn = sf * creg + si * tanh_f(gg);
      float hn = so * tanh_f(cn);
      creg = cn;
      hreg = hn;
      hsh[hwrite] = (_Float16)hn;
      out[((size_t)row * T + t) * ostride + dir * H + u] = __float2bfloat16(hn);
    }
    __syncthreads();
  }

  if (final_h != nullptr && u < 200) {
    // glob_h = [hb1 | hf1]: backward dir -> cols 0..199, forward -> 200..399
    int col = dir ? u : (H + u);
    final_h[(size_t)row * 400 + col] = hreg;
  }
}

// ---------------------------------------------------------------------------
// Span sums v2: chunked (t-chunk x d-octet) with bf16x8 row loads.
// Threads: tc = tid>>6 (t-chunk of 64), dv = tid&63 (d-octet, active < 50).
// Flag loads are wave-uniform (scalar); rows loaded only on span hits.
__global__ __launch_bounds__(256) void span_sum(
    const __hip_bfloat16* __restrict__ rnn,   // [B][T][400]
    const int* __restrict__ masks,
    const int* __restrict__ subj_pos,
    const int* __restrict__ obj_pos,
    float* __restrict__ obj_h,   // [B][400]
    float* __restrict__ subj_h)  // [B][400]
{
  int b = blockIdx.x;
  int tc = threadIdx.x >> 6;
  int dv = threadIdx.x & 63;
  __shared__ float aS[4][400];
  __shared__ float aO[4][400];

  float ss[8] = {}, so[8] = {};
  if (dv < 50) {
    for (int t = tc * 64; t < tc * 64 + 64; ++t) {
      int m = masks[b * T + t];
      int fs = (subj_pos[b * T + t] + m) == 0;
      int fo = (obj_pos[b * T + t] + m) == 0;
      if (fs | fo) {
        uix4 v = *(const uix4*)(rnn + ((size_t)b * T + t) * 400 + dv * 8);
        #pragma unroll
        for (int j = 0; j < 4; ++j) {
          float lo = bfr2f((unsigned short)(v[j] & 0xFFFF));
          float hi = bfr2f((unsigned short)(v[j] >> 16));
          if (fs) { ss[2 * j] += lo; ss[2 * j + 1] += hi; }
          if (fo) { so[2 * j] += lo; so[2 * j + 1] += hi; }
        }
      }
    }
    #pragma unroll
    for (int k = 0; k < 8; ++k) {
      aS[tc][dv * 8 + k] = ss[k];
      aO[tc][dv * 8 + k] = so[k];
    }
  }
  __syncthreads();
  for (int d = threadIdx.x; d < 400; d += 256) {
    subj_h[(size_t)b * 400 + d] = aS[0][d] + aS[1][d] + aS[2][d] + aS[3][d];
    obj_h[(size_t)b * 400 + d]  = aO[0][d] + aO[1][d] + aO[2][d] + aO[3][d];
  }
}

// ---------------------------------------------------------------------------
// Single-query attention pooling v2. grid = 3*128 (qi = blk>>7, b = blk&127).
// Phase 1 vectorized to bf16x8 row loads; phase 2 restructured to chunked
// (t-chunk x d-octet) coalesced loads + LDS 4-way combine. Pad steps skip
// wave-uniformly (ps == 0 exactly: exp(-1e9 - mx) underflows).
__global__ __launch_bounds__(256) void attn_pool_k(
    const float* __restrict__ qbuf,           // [3][B][400]
    const __hip_bfloat16* __restrict__ rnn,   // [B][T][400]
    const int* __restrict__ masks,
    float* __restrict__ outp)                 // [3][B][400]
{
  int b = blockIdx.x & 127;
  int qi = blockIdx.x >> 7;
  __shared__ float qs[400];
  __shared__ float ps[256];
  __shared__ float red[256];
  __shared__ float acc4[4][400];
  const float* q = qbuf + ((size_t)qi * B + b) * 400;
  for (int d = threadIdx.x; d < 400; d += 256) qs[d] = q[d];
  __syncthreads();

  int t = threadIdx.x;
  const uix4* kvv = (const uix4*)(rnn + ((size_t)b * T + t) * 400);
  float s = 0.f;
  #pragma unroll 5
  for (int i = 0; i < 50; ++i) {
    uix4 v = kvv[i];
    #pragma unroll
    for (int j = 0; j < 4; ++j) {
      s += bfr2f((unsigned short)(v[j] & 0xFFFF)) * qs[8 * i + 2 * j];
      s += bfr2f((unsigned short)(v[j] >> 16))    * qs[8 * i + 2 * j + 1];
    }
  }
  s *= 0.05f;  // 1/sqrt(400)
  if (masks[b * T + t] != 0) s = -1e9f;

  red[t] = s;
  __syncthreads();
  for (int off = 128; off > 0; off >>= 1) {
    if (t < off) red[t] = fmaxf(red[t], red[t + off]);
    __syncthreads();
  }
  float mx = red[0];
  __syncthreads();
  float e = expf(s - mx);
  red[t] = e;
  __syncthreads();
  for (int off = 128; off > 0; off >>= 1) {
    if (t < off) red[t] += red[t + off];
    __syncthreads();
  }
  float inv = 1.0f / red[0];
  ps[t] = e * inv;
  __syncthreads();

  // --- phase 2: out[d] = sum_t ps[t] * rnn[t][d], chunked ---
  int tc = threadIdx.x >> 6;
  int dv = threadIdx.x & 63;
  float a[8] = {};
  if (dv < 50) {
    for (int t2 = tc * 64; t2 < tc * 64 + 64; ++t2) {
      float wgt = ps[t2];              // wave-uniform (LDS broadcast)
      if (wgt != 0.f) {
        uix4 v = *(const uix4*)(rnn + ((size_t)b * T + t2) * 400 + dv * 8);
        #pragma unroll
        for (int j = 0; j < 4; ++j) {
          a[2 * j]     += wgt * bfr2f((unsigned short)(v[j] & 0xFFFF));
          a[2 * j + 1] += wgt * bfr2f((unsigned short)(v[j] >> 16));
        }
      }
    }
    #pragma unroll
    for (int k = 0; k < 8; ++k) acc4[tc][dv * 8 + k] = a[k];
  }
  __syncthreads();
  for (int d = threadIdx.x; d < 400; d += 256)
    outp[((size_t)qi * B + b) * 400 + d] =
        acc4[0][d] + acc4[1][d] + acc4[2][d] + acc4[3][d];
}

// ---------------------------------------------------------------------------
// Head — reads all weights raw (flag-dispatched), writes bf16 or f32 per flag
__global__ __launch_bounds__(256) void final_head(
    const float* __restrict__ attn,   // [3][B][400]: 0=obj,1=subj,2=glob
    const void* __restrict__ wo_w, const void* __restrict__ wo_b,
    const void* __restrict__ ws_w, const void* __restrict__ ws_b,
    const void* __restrict__ wg_w, const void* __restrict__ wg_b,
    const void* __restrict__ cls_w, const void* __restrict__ cls_b,
    void* __restrict__ outp,          // [B][2]
    const int* __restrict__ flag)
{
  int b = blockIdx.x;
  int f = *flag;
  __shared__ float hs[H];
  int j = threadIdx.x;
  if (j < H) {
    float acc = ldraw(wo_b, j, f) + ldraw(ws_b, j, f) + ldraw(wg_b, j, f);
    const float* oa = attn + ((size_t)0 * B + b) * 400;
    const float* sa = attn + ((size_t)1 * B + b) * 400;
    const float* ga = attn + ((size_t)2 * B + b) * 400;
    for (int d = 0; d < 400; ++d) {
      acc += oa[d] * ldraw(wo_w, (size_t)j * 400 + d, f);
      acc += sa[d] * ldraw(ws_w, (size_t)j * 400 + d, f);
      acc += ga[d] * ldraw(wg_w, (size_t)j * 400 + d, f);
    }
    hs[j] = fmaxf(acc, 0.0f);
  }
  __syncthreads();
  if (j < 2) {
    float a = ldraw(cls_b, j, f);
    for (int k = 0; k < H; ++k)
      a += hs[k] * ldraw(cls_w, (size_t)j * H + k, f);
    if (f) ((float*)outp)[b * 2 + j] = a;
    else   ((__hip_bfloat16*)outp)[b * 2 + j] = __float2bfloat16(a);
  }
}

// ---------------------------------------------------------------------------
// Workspace layout (bytes)
constexpr size_t O_X0   = 0;            // 32768*384*2  = 25165824
constexpr size_t O_X1   = 25165824;     // 32768*416*2  = 27262976
constexpr size_t O_GPRE = 52428800;     // 32768*1600*2 = 104857600
constexpr size_t O_RNN  = 157286400;    // 32768*400*2  = 26214400
constexpr size_t O_WIH0 = 183500800;    // 1600*384*2   = 1228800
constexpr size_t O_WIH1 = 184729600;    // 1600*416*2   = 1331200
constexpr size_t O_WPK  = 186060800;    // 4*800*100*4  = 1280000
constexpr size_t O_Q    = 187340800;    // 3*128*400*4  = 614400
constexpr size_t O_ATT  = 187955200;    // 614400
constexpr size_t O_FLAG = 188569600;    // 256

extern "C" void kernel_launch(void* const* d_in, const int* in_sizes, int n_in,
                              void* d_out, int out_size, void* d_ws, size_t ws_size,
                              hipStream_t stream) {
  (void)in_sizes; (void)n_in; (void)out_size; (void)ws_size;

  const int* words = (const int*)d_in[0];
  const int* masks = (const int*)d_in[1];
  const int* pos   = (const int*)d_in[2];
  const int* ner   = (const int*)d_in[3];
  const int* subj  = (const int*)d_in[4];
  const int* obj   = (const int*)d_in[5];
  const void* emb_w = d_in[6];
  const void* pos_w = d_in[7];
  const void* ner_w = d_in[8];
  const void* wih[4]  = {d_in[9],  d_in[12], d_in[15], d_in[18]};
  const void* whh[4]  = {d_in[10], d_in[13], d_in[16], d_in[19]};
  const void* bias[4] = {d_in[11], d_in[14], d_in[17], d_in[20]};
  const void* wo_w = d_in[21]; const void* wo_b = d_in[22];
  const void* ws_w = d_in[23]; const void* ws_b = d_in[24];
  const void* wg_w = d_in[25]; const void* wg_b = d_in[26];
  const void* cls_w = d_in[27]; const void* cls_b = d_in[28];

  char* ws = (char*)d_ws;
  __hip_bfloat16* X0   = (__hip_bfloat16*)(ws + O_X0);
  __hip_bfloat16* X1   = (__hip_bfloat16*)(ws + O_X1);
  __hip_bfloat16* Gpre = (__hip_bfloat16*)(ws + O_GPRE);   // [BT][1600]
  __hip_bfloat16* RNN  = (__hip_bfloat16*)(ws + O_RNN);
  __hip_bfloat16* wih0p = (__hip_bfloat16*)(ws + O_WIH0);  // [1600][384]
  __hip_bfloat16* wih1p = (__hip_bfloat16*)(ws + O_WIH1);  // [1600][416]
  unsigned* Wpack = (unsigned*)(ws + O_WPK);               // [4][800][100]
  float* qbuf = (float*)(ws + O_Q);    // [3][B][400]: obj, subj, glob
  float* attb = (float*)(ws + O_ATT);  // [3][B][400]
  int* flag = (int*)(ws + O_FLAG);

  // --- dtype detect + weight prep (all read raw, flag-dispatched) ---
  detect_dtype<<<1, 256, 0, stream>>>((const unsigned short*)emb_w, flag);
  pack_whh4<<<1250, 256, 0, stream>>>(whh[0], whh[1], whh[2], whh[3], Wpack, flag);
  pad_copy2<<<1600, 128, 0, stream>>>(wih[0], wih[1], wih0p, K0, K0P, flag);
  pad_copy2<<<1600, 128, 0, stream>>>(wih[2], wih[3], wih1p, K1, K1P, flag);

  // --- embedding + output-buffer zero fills (lstm skips padded steps) ---
  embed_kernel<<<BT, 128, 0, stream>>>(words, pos, ner, emb_w, pos_w, ner_w, X0, flag);
  fill_zero<<<1024, 256, 0, stream>>>((uix4*)X1, (size_t)BT * K1P * 2 / 16);
  fill_zero<<<1024, 256, 0, stream>>>((uix4*)RNN, (size_t)BT * 400 * 2 / 16);

  dim3 ggrid(BT / 64, 13);  // N = 1600, 128-wide n-tiles (both dirs fused)

  // --- layer 0 ---
  gemm_bt<<<ggrid, 256, 0, stream>>>(X0, wih0p, Gpre, 1600, K0P);
  lstm_row<<<256, 512, 0, stream>>>(Gpre, Wpack, bias[0], bias[1], masks,
                                    X1, K1P, nullptr, flag);

  // --- layer 1 ---
  gemm_bt<<<ggrid, 256, 0, stream>>>(X1, wih1p, Gpre, 1600, K1P);
  float* qglob = qbuf + (size_t)2 * B * 400;
  lstm_row<<<256, 512, 0, stream>>>(Gpre, Wpack + (size_t)2 * G4 * 100,
                                    bias[2], bias[3], masks,
                                    RNN, 400, qglob, flag);

  // --- span sums (obj -> slot0, subj -> slot1) ---
  span_sum<<<B, 256, 0, stream>>>(RNN, masks, subj, obj,
                                  qbuf, qbuf + (size_t)B * 400);

  // --- attention pooling (3 queries) ---
  attn_pool_k<<<3 * B, 256, 0, stream>>>(qbuf, RNN, masks, attb);

  // --- head (raw weights) ---
  final_head<<<B, 256, 0, stream>>>(attb, wo_w, wo_b, ws_w, ws_b, wg_w, wg_b,
                                    cls_w, cls_b, d_out, flag);
}